// Round 7
// baseline (256.220 us; speedup 1.0000x reference)
//
#include <hip/hip_runtime.h>
#include <hip/hip_bf16.h>
#include <stdint.h>

// Problem constants
#define Bn  4
#define Nn  10000
#define KRn 5
#define KAn 8
#define Cn  32
#define On  64
#define Kk  2
#define RN  8                  // rotations = KA
#define MT  16                 // points per block (10000 = 625*16, exact)
#define LDX 264                // LDS row stride (bf16 elems): 256 + 8 pad

typedef __attribute__((ext_vector_type(8))) short bf16x8;
typedef __attribute__((ext_vector_type(4))) float f32x4;
typedef __attribute__((ext_vector_type(2))) float f32x2;

static __device__ __forceinline__ unsigned int bfpack2(float a, float b) {
  unsigned int ua = __builtin_bit_cast(unsigned int, a);
  unsigned int ub = __builtin_bit_cast(unsigned int, b);
  ua = (ua + 0x7FFFu + ((ua >> 16) & 1u)) >> 16;
  ub = (ub + 0x7FFFu + ((ub >> 16) & 1u)) >> 16;
  return ua | (ub << 16);
}
static __device__ __forceinline__ unsigned short bf1(float a) {
  unsigned int ua = __builtin_bit_cast(unsigned int, a);
  return (unsigned short)((ua + 0x7FFFu + ((ua >> 16) & 1u)) >> 16);
}

// Un-rotated summed kernel, B-fragment-ready:
//   wk[p][q'][ot][lane][j] = sum_g kernels[g, p, q', o, c]
//   o = ot*16 + (lane&15), c = (lane>>4)*8 + j
__global__ void prep_kernel(const float* __restrict__ kernels,
                            const float* __restrict__ bias,
                            unsigned short* __restrict__ wk,
                            float* __restrict__ bconst) {
  int tid = blockIdx.x * 256 + threadIdx.x;
  if (tid < KRn * KAn * 4 * 64) {
    int lane = tid & 63;
    int ot   = (tid >> 6) & 3;
    int q    = (tid >> 8) & 7;
    int p    = tid >> 11;
    int o  = ot * 16 + (lane & 15);
    int cb = (lane >> 4) * 8;
    const float* k0 = kernels + (((p * KAn + q) * On + o) * Cn + cb);
    const float* k1 = k0 + KRn * KAn * On * Cn;  // g=1
    unsigned short v[8];
#pragma unroll
    for (int j = 0; j < 8; ++j) v[j] = bf1(k0[j] + k1[j]);
    reinterpret_cast<bf16x8*>(wk)[tid] = *reinterpret_cast<const bf16x8*>(v);
  }
  if (blockIdx.x == 0 && threadIdx.x < On) {
    float s = 0.f;
    for (int pq = 0; pq < KRn * KAn; ++pq) s += bias[pq * On + (int)threadIdx.x];
    bconst[threadIdx.x] = (float)Kk * s;
  }
}

// Occupancy-maximized fused kernel: MT=16 (32 AGPR acc), single 8.25 KB LDS
// buffer, no bary staging (direct wave-uniform loads) -> ~6 blocks/CU;
// cross-block TLP hides gather latency instead of intra-block pipelining.
__global__ __launch_bounds__(256, 6) void conv_kernel(
    const float* __restrict__ signal,
    const float* __restrict__ bary,
    const unsigned short* __restrict__ wk,
    const float* __restrict__ bconst,
    float* __restrict__ out) {
  __shared__ __align__(16) unsigned short xs[MT * LDX];  // 8.25 KB

  const int b    = blockIdx.y;
  const int m0   = blockIdx.x * MT;
  const int tid  = threadIdx.x;
  const int lane = tid & 63;
  const int wv   = tid >> 6;           // wave 0..3
  const int lm   = lane & 15;
  const int lg   = lane >> 4;
  const int sq   = lane >> 3;          // q of this 8-lane group
  const int cv4  = (lane & 7) * 4;     // channel offset (floats)

  const float* sigb  = signal + (size_t)b * Nn * Cn;
  const float* baryb = bary + (size_t)b * Nn * 240;
  const bf16x8* wkf  = reinterpret_cast<const bf16x8*>(wk);

  f32x4 acc[2][4];                     // [rr][ot] -> 32 regs
#pragma unroll
  for (int rr = 0; rr < 2; ++rr)
#pragma unroll
    for (int ot = 0; ot < 4; ++ot) acc[rr][ot] = (f32x4){0.f, 0.f, 0.f, 0.f};

  for (int p = 0; p < KRn; ++p) {
    __syncthreads();                   // previous chunk's reads done
    // ---- stage chunk p: gather+interp -> xs (each wave: 4 points) ----
#pragma unroll
    for (int k = 0; k < 4; ++k) {
      int pt = k * 4 + wv;
      const float* bb = baryb + (size_t)(m0 + pt) * 240 + p * 48 + sq * 6;
      f32x2 p0 = *(const f32x2*)(bb);
      f32x2 p1 = *(const f32x2*)(bb + 2);
      f32x2 p2 = *(const f32x2*)(bb + 4);
      f32x4 s0 = *(const f32x4*)(sigb + (size_t)(int)p0.x * Cn + cv4);
      f32x4 s1 = *(const f32x4*)(sigb + (size_t)(int)p1.x * Cn + cv4);
      f32x4 s2 = *(const f32x4*)(sigb + (size_t)(int)p2.x * Cn + cv4);
      f32x4 v = p0.y * s0 + p1.y * s1 + p2.y * s2;
      unsigned long long pk = (unsigned long long)bfpack2(v.x, v.y) |
                              ((unsigned long long)bfpack2(v.z, v.w) << 32);
      *(unsigned long long*)(&xs[pt * LDX + sq * 32 + cv4]) = pk;
    }
    __syncthreads();                   // xs fully staged
    // ---- GEMM chunk p: loop over q' with rotation-by-index ----
#pragma unroll
    for (int qp = 0; qp < 8; ++qp) {
      const bf16x8* wp = wkf + (size_t)(p * 8 + qp) * 256 + lane;
      bf16x8 Bf0 = wp[0], Bf1 = wp[64], Bf2 = wp[128], Bf3 = wp[192];
#pragma unroll
      for (int rr = 0; rr < 2; ++rr) {
        int q = (qp - (wv * 2 + rr)) & 7;  // rotation: chunk q -> output ring r
        bf16x8 a = *(const bf16x8*)(&xs[lm * LDX + q * 32 + lg * 8]);
        acc[rr][0] = __builtin_amdgcn_mfma_f32_16x16x32_bf16(a, Bf0, acc[rr][0], 0, 0, 0);
        acc[rr][1] = __builtin_amdgcn_mfma_f32_16x16x32_bf16(a, Bf1, acc[rr][1], 0, 0, 0);
        acc[rr][2] = __builtin_amdgcn_mfma_f32_16x16x32_bf16(a, Bf2, acc[rr][2], 0, 0, 0);
        acc[rr][3] = __builtin_amdgcn_mfma_f32_16x16x32_bf16(a, Bf3, acc[rr][3], 0, 0, 0);
      }
    }
  }

  // ---- epilogue: out[b, r, n, o] = acc + bconst[o]  (no tail: 625*16=10000) ----
#pragma unroll
  for (int rr = 0; rr < 2; ++rr) {
    int r = wv * 2 + rr;
#pragma unroll
    for (int ot = 0; ot < 4; ++ot) {
      int o = ot * 16 + lm;
      float bc = bconst[o];
      float* outp = out + (((size_t)b * RN + r) * Nn + m0 + lg * 4) * On + o;
#pragma unroll
      for (int i = 0; i < 4; ++i)
        outp[(size_t)i * On] = acc[rr][ot][i] + bc;
    }
  }
}

extern "C" void kernel_launch(void* const* d_in, const int* in_sizes, int n_in,
                              void* d_out, int out_size, void* d_ws, size_t ws_size,
                              hipStream_t stream) {
  const float* signal  = (const float*)d_in[0];
  const float* bary    = (const float*)d_in[1];
  const float* kernels = (const float*)d_in[2];
  const float* bias    = (const float*)d_in[3];
  float* out = (float*)d_out;

  unsigned short* wk = (unsigned short*)d_ws;
  float* bconst = (float*)((char*)d_ws + (size_t)KRn * KAn * 4 * 64 * 8 * 2);

  hipLaunchKernelGGL(prep_kernel, dim3(40), dim3(256), 0, stream,
                     kernels, bias, wk, bconst);
  dim3 grid(Nn / MT, Bn);
  hipLaunchKernelGGL(conv_kernel, grid, dim3(256), 0, stream,
                     signal, bary, wk, bconst, out);
}